// Round 14
// baseline (301.241 us; speedup 1.0000x reference)
//
#include <hip/hip_runtime.h>
#include <hip/hip_fp16.h>

#define N_NODES 100000
#define N_EDGES 1600000
#define DIN 24
#define DH 64
#define DOUT 12
#define NEG_SLOPE 0.01f
#define NG 64                      // edge chunks
#define EPG (N_EDGES / NG)         // 25000 edges per chunk
#define NS 4                       // node slices for LDS hist (32KB counters)
#define SLICE_N 32768              // nodes per slice
#define NTOT (NG * N_NODES)        // 6.4M (chunk,node) byte counters
#define SCAN_BLK 4096
#define LDSW 72

// role block counts
#define NB_HIST (NS * NG)                        // 256 (1024-thread blocks in D1)
#define NB_SUMDEG ((N_NODES + 255) / 256)               // 391
#define NB_SCAN1N ((N_NODES + SCAN_BLK - 1) / SCAN_BLK) // 25
#define NB_SCAT4 ((N_EDGES / 4 + 1023) / 1024)   // 391 (1024-thr, 4 edges/thread)
#define NB_NODE ((N_NODES + 63) / 64)            // 1563 tiles of 64 nodes
#define NB_NME ((NB_NODE + 7) / 8)               // 196 1024-thr blocks, 8 tiles each (L1)
#define NB_AGGG (N_NODES / 16)                   // 6250 (512-thr, 16 nodes, exact)
#define NB_AGG ((N_NODES + 7) / 8)               // 12500 (final layer)

// smem partition for the D5 union
#define SM_WEMB 18432
#define SM_BIAS 23552
#define SM_HBUF 23808
#define SM_SIZE 60672

typedef _Float16 half8_t __attribute__((ext_vector_type(8)));
typedef float floatx4 __attribute__((ext_vector_type(4)));

// ---------------- role bodies ----------------
__device__ __forceinline__ void dev_consts(const float* emb_e_W, const float* emb_e_b,
                                           const float* attn1, const float* attn2,
                                           float* consts) {
    int lane = threadIdx.x;
    if (lane >= 64) return;
    float w = emb_e_W[lane], b = emb_e_b[lane];
    float a1 = attn1[2 * DH + lane], a2 = attn2[2 * DH + lane];
    float c11 = w * a1, c01 = b * a1, c12 = w * a2, c02 = b * a2;
    for (int off = 32; off; off >>= 1) {
        c11 += __shfl_down(c11, off);
        c01 += __shfl_down(c01, off);
        c12 += __shfl_down(c12, off);
        c02 += __shfl_down(c02, off);
    }
    if (lane == 0) {
        consts[0] = c11; consts[1] = c01; consts[2] = c12; consts[3] = c02;
    }
}

// slice-LDS histogram + rank capture, ZERO global atomics.
__device__ __forceinline__ void dev_hist(int bid, char* smem, const int* dst,
                                         unsigned char* deg, unsigned char* rank) {
    unsigned* cnt = (unsigned*)smem;        // 32 KB byte-packed counters
    int s = bid % NS, c = bid / NS;
    for (int i = threadIdx.x; i < SLICE_N / 4; i += 1024) cnt[i] = 0;
    __syncthreads();
    int nbase = s * SLICE_N;
    int start = c * EPG, end = start + EPG;
    for (int i = start + threadIdx.x; i < end; i += 1024) {
        int local = dst[i] - nbase;
        if ((unsigned)local < SLICE_N) {
            unsigned sh = (unsigned)(local & 3) * 8u;
            unsigned old = atomicAdd(&cnt[local >> 2], 1u << sh);  // LDS atomic
            rank[i] = (unsigned char)((old >> sh) & 255u);
        }
    }
    __syncthreads();
    int nmax = N_NODES - nbase;
    if (nmax > SLICE_N) nmax = SLICE_N;
    unsigned* dw = (unsigned*)(deg + (size_t)c * N_NODES + nbase);
    for (int l = threadIdx.x; l < (nmax >> 2); l += 1024) dw[l] = cnt[l];
}

__device__ __forceinline__ void dev_scan1(int bid, const int* in, int* out,
                                          int* part, int n) {
    __shared__ int lds[256];
    int t = threadIdx.x;
    int base = bid * SCAN_BLK + t * 16;
    int v[16];
    int s = 0;
#pragma unroll
    for (int i = 0; i < 16; ++i) {
        int idx = base + i;
        v[i] = (idx < n) ? in[idx] : 0;
        s += v[i];
    }
    lds[t] = s;
    __syncthreads();
    for (int off = 1; off < 256; off <<= 1) {
        int y = (t >= off) ? lds[t - off] : 0;
        __syncthreads();
        lds[t] += y;
        __syncthreads();
    }
    int run = lds[t] - s;
#pragma unroll
    for (int i = 0; i < 16; ++i) {
        int idx = base + i;
        if (idx < n) out[idx] = run;
        run += v[i];
    }
    if (t == 255) part[bid] = lds[255];
}

// degN + per-node chunk prefix (byte)
__device__ __forceinline__ void dev_sumdeg(int bid, const unsigned char* degB,
                                           int* degN, unsigned char* chunkOff) {
    int n = bid * 256 + threadIdx.x;
    if (n >= N_NODES) return;
    int run = 0;
    for (int g = 0; g < NG; ++g) {
        size_t idx = (size_t)g * N_NODES + n;
        int v = (int)degB[idx];
        chunkOff[idx] = (unsigned char)run;
        run += v;
    }
    degN[n] = run;
}

// scatter role for the 1024-thr fused D5: 4 consecutive edges/thread.
__device__ __forceinline__ void dev_scat4(int bid, const int* src, const int* dst,
                                          const float* e_w, const unsigned char* rank,
                                          const int* rowStart,
                                          const unsigned char* chunkOff,
                                          unsigned* csr2) {
    int e4 = (bid * 1024 + threadIdx.x) * 4;
    if (e4 >= N_EDGES) return;
    int g = e4 / EPG;                       // EPG%4==0: group never straddles chunks
    const unsigned char* co = chunkOff + (size_t)g * N_NODES;
    int4   d4 = *(const int4*)(dst + e4);
    int4   s4 = *(const int4*)(src + e4);
    float4 w4 = *(const float4*)(e_w + e4);
    unsigned r4 = *(const unsigned*)(rank + e4);
    int b0 = rowStart[d4.x] + (int)co[d4.x];
    int b1 = rowStart[d4.y] + (int)co[d4.y];
    int b2 = rowStart[d4.z] + (int)co[d4.z];
    int b3 = rowStart[d4.w] + (int)co[d4.w];
    unsigned q0 = (unsigned)(w4.x * 32768.f); if (q0 > 32767u) q0 = 32767u;
    unsigned q1 = (unsigned)(w4.y * 32768.f); if (q1 > 32767u) q1 = 32767u;
    unsigned q2 = (unsigned)(w4.z * 32768.f); if (q2 > 32767u) q2 = 32767u;
    unsigned q3 = (unsigned)(w4.w * 32768.f); if (q3 > 32767u) q3 = 32767u;
    csr2[b0 + (r4 & 255u)]         = (unsigned)s4.x | (q0 << 17);
    csr2[b1 + ((r4 >> 8) & 255u)]  = (unsigned)s4.y | (q1 << 17);
    csr2[b2 + ((r4 >> 16) & 255u)] = (unsigned)s4.z | (q2 << 17);
    csr2[b3 + (r4 >> 24)]          = (unsigned)s4.w | (q3 << 17);
}

// L1 node GEMM + fused embed, 1024-thread/16-wave variant.
__device__ __forceinline__ void dev_nodeME(int bid, char* smem,
                                           const float* feats, const float* embW,
                                           const float* embB,
                                           const float* Wself, const float* Wfunc,
                                           const float* attn,
                                           __half* h16, __half* zh, __half* hs16,
                                           float* s_src, float* s_dst) {
    _Float16* lds   = (_Float16*)smem;                 // 2*64*LDSW weights
    _Float16* wembH = (_Float16*)(smem + SM_WEMB);     // 64*40 embed W (k pad 32)
    float*    biasS = (float*)(smem + SM_BIAS);        // 64
    _Float16* hbufA = (_Float16*)(smem + SM_HBUF);     // 16 x [16*72] per-wave h tiles
    int tid = threadIdx.x;
    for (int idx = tid; idx < 2 * 64 * 64; idx += 1024) {
        int mat = idx >> 12, rem = idx & 4095;
        int o = rem >> 6, k = rem & 63;
        float v = mat ? Wfunc[rem] : Wself[rem];
        lds[(mat * 64 + o) * LDSW + k] = (_Float16)v;
    }
    for (int idx = tid; idx < 64 * 32; idx += 1024) {
        int o = idx >> 5, k = idx & 31;
        wembH[o * 40 + k] = (_Float16)((k < DIN) ? embW[o * DIN + k] : 0.f);
    }
    if (tid < 64) biasS[tid] = embB[tid];
    __syncthreads();

    int wave = tid >> 6, lane = tid & 63;
    int vb = wave >> 2, wv = wave & 3;
    int quad = lane >> 4, lm = lane & 15;
    float asv[4], adv[4];
#pragma unroll
    for (int t = 0; t < 4; ++t) {
        asv[t] = attn[t * 16 + lm];
        adv[t] = attn[DH + t * 16 + lm];
    }
    const _Float16* bS = lds;
    const _Float16* bF = lds + 64 * LDSW;
    _Float16* hb = hbufA + wave * (16 * 72);

    for (int tb = bid * 4 + vb; tb < NB_NODE; tb += NB_NME * 4) {
        int n0 = (tb * 4 + wv) * 16;
        if (n0 >= N_NODES) continue;

        // ---- embed MFMA: A = feats rows (k = quad*8+j, valid k<24) ----
        half8_t afE;
#pragma unroll
        for (int j = 0; j < 8; ++j) afE[j] = (_Float16)0.f;
        if (quad < 3) {
            const float* f = feats + (size_t)(n0 + lm) * DIN + quad * 8;
            float4 q0 = *(const float4*)(f);
            float4 q1 = *(const float4*)(f + 4);
            afE[0] = (_Float16)q0.x; afE[1] = (_Float16)q0.y;
            afE[2] = (_Float16)q0.z; afE[3] = (_Float16)q0.w;
            afE[4] = (_Float16)q1.x; afE[5] = (_Float16)q1.y;
            afE[6] = (_Float16)q1.z; afE[7] = (_Float16)q1.w;
        }
        floatx4 accE[4];
#pragma unroll
        for (int t = 0; t < 4; ++t) accE[t] = (floatx4)0.f;
#pragma unroll
        for (int t = 0; t < 4; ++t) {
            int o = t * 16 + lm;
            half8_t bE = *(const half8_t*)(wembH + o * 40 + quad * 8);
            accE[t] = __builtin_amdgcn_mfma_f32_16x16x32_f16(afE, bE, accE[t], 0, 0, 0);
        }
        // bias + write h16 global (residual) + LDS hbuf (A-frag source)
#pragma unroll
        for (int t = 0; t < 4; ++t) {
            float bv = biasS[t * 16 + lm];
#pragma unroll
            for (int r = 0; r < 4; ++r) {
                float hv = accE[t][r] + bv;
                int node = n0 + quad * 4 + r;
                h16[(size_t)node * DH + t * 16 + lm] = __float2half(hv);
                hb[(quad * 4 + r) * 72 + t * 16 + lm] = (_Float16)hv;
            }
        }
        // same wave wrote all 16 rows of hb -> lockstep read, no barrier
        half8_t afrag[2];
#pragma unroll
        for (int ks = 0; ks < 2; ++ks)
            afrag[ks] = *(const half8_t*)(hb + lm * 72 + ks * 32 + quad * 8);

        floatx4 accS[4], accF[4];
#pragma unroll
        for (int t = 0; t < 4; ++t) { accS[t] = (floatx4)0.f; accF[t] = (floatx4)0.f; }
#pragma unroll
        for (int t = 0; t < 4; ++t) {
            int o = t * 16 + lm;
#pragma unroll
            for (int ks = 0; ks < 2; ++ks) {
                int hoff = o * LDSW + ks * 32 + quad * 8;
                half8_t b1 = *(const half8_t*)(bS + hoff);
                half8_t b2 = *(const half8_t*)(bF + hoff);
                accS[t] = __builtin_amdgcn_mfma_f32_16x16x32_f16(afrag[ks], b1, accS[t], 0, 0, 0);
                accF[t] = __builtin_amdgcn_mfma_f32_16x16x32_f16(afrag[ks], b2, accF[t], 0, 0, 0);
            }
        }

        float ps[4] = {0.f, 0.f, 0.f, 0.f}, pd[4] = {0.f, 0.f, 0.f, 0.f};
#pragma unroll
        for (int t = 0; t < 4; ++t) {
#pragma unroll
            for (int r = 0; r < 4; ++r) {
                int node = n0 + quad * 4 + r;
                float zv = accF[t][r];
                zh[(size_t)node * DH + t * 16 + lm] = __float2half(zv);
                hs16[(size_t)node * DH + t * 16 + lm] = __float2half(accS[t][r]);
                ps[r] += zv * asv[t];
                pd[r] += zv * adv[t];
            }
        }
#pragma unroll
        for (int r = 0; r < 4; ++r) {
            float p1 = ps[r], p2 = pd[r];
            for (int off = 8; off; off >>= 1) {
                p1 += __shfl_xor(p1, off);
                p2 += __shfl_xor(p2, off);
            }
            if (lm == 0) {
                s_src[n0 + quad * 4 + r] = p1;
                s_dst[n0 + quad * 4 + r] = p2;
            }
        }
    }
}

// ---------------- fused dispatches ----------------
// D1 (1024 thr): consts | hist only (32KB LDS)
__global__ void __launch_bounds__(1024, 2)
k_fuse1(const int* __restrict__ dst, unsigned char* __restrict__ deg,
        unsigned char* __restrict__ rank,
        const float* __restrict__ emb_e_W, const float* __restrict__ emb_e_b,
        const float* __restrict__ attn1, const float* __restrict__ attn2,
        float* __restrict__ consts) {
    __shared__ __align__(16) char smem[SLICE_N];
    int bid = blockIdx.x;
    if (bid == 0) { dev_consts(emb_e_W, emb_e_b, attn1, attn2, consts); return; }
    dev_hist(bid - 1, smem, dst, deg, rank);
}

// D2: sumdeg + chunkOff prefix
__global__ void k_prep2(const unsigned char* __restrict__ degB, int* __restrict__ degN,
                        unsigned char* __restrict__ chunkOff) {
    dev_sumdeg(blockIdx.x, degB, degN, chunkOff);
}

// D3: scan1N
__global__ void k_prep3(const int* __restrict__ degN, int* __restrict__ row_offN,
                        int* __restrict__ partN) {
    dev_scan1(blockIdx.x, degN, row_offN, partN, N_NODES);
}

// D4: rowStart finalize with INLINE partN scan
__global__ void k_prep4(const int* __restrict__ row_offN, const int* __restrict__ partN,
                        int* __restrict__ rowStart) {
    __shared__ int pfx[32];
    int t = threadIdx.x;
    if (t < 64) {
        int v = (t < NB_SCAN1N) ? partN[t] : 0;
        int x = v;
#pragma unroll
        for (int s = 1; s < 32; s <<= 1) {
            int y = __shfl_up(x, s);
            if (t >= s) x += y;
        }
        if (t < 32) pfx[t] = x - v;   // exclusive prefix
    }
    __syncthreads();
    int n = blockIdx.x * 256 + t;
    if (n < N_NODES) rowStart[n] = row_offN[n] + pfx[n >> 12];
    if (n == 0) rowStart[N_NODES] = N_EDGES;
}

// D5 (1024 thr): node GEMM L1(+embed) | scatter (co-resident; round-13 verified:
// 66us ~= max(45,53) instead of 98us serial)
__global__ void __launch_bounds__(1024, 2)
k_fuse5(const float* __restrict__ feats, const float* __restrict__ embW,
        const float* __restrict__ embB,
        __half* __restrict__ h16, const float* __restrict__ Wself1,
        const float* __restrict__ Wfunc1, const float* __restrict__ attn1,
        __half* __restrict__ zh, __half* __restrict__ hs16,
        float* __restrict__ s_src, float* __restrict__ s_dst,
        const int* __restrict__ src, const int* __restrict__ dst,
        const float* __restrict__ e_w, const unsigned char* __restrict__ rank,
        const int* __restrict__ rowStart,
        const unsigned char* __restrict__ chunkOff, unsigned* __restrict__ csr2) {
    __shared__ __align__(16) char smem[SM_SIZE];
    int bid = blockIdx.x;
    if (bid < NB_NME) {
        dev_nodeME(bid, smem, feats, embW, embB, Wself1, Wfunc1, attn1,
                   h16, zh, hs16, s_src, s_dst);
        return;
    }
    dev_scat4(bid - NB_NME, src, dst, e_w, rank, rowStart, chunkOff, csr2);
}

// D6 (512 thr, 16 nodes/block, exact fit): agg L1 + FUSED L2 node GEMM.
// Round-27: nodeL's GEMM is per-node independent and aggL1 holds h_new at its
// epilogue -> stash h_new in a 16x72 LDS A-frag buffer, barrier, wave0 runs the
// 16-node MFMA tile. Outputs to SEPARATE buffers (zh2/hs2/s2) since other
// blocks still gather the L1 zh concurrently. Kills the nodeL dispatch + gap.
__global__ void __launch_bounds__(512, 6)
k_aggG(const int* __restrict__ rowStart, const unsigned* __restrict__ csr,
       const float* __restrict__ s_src, const float* __restrict__ s_dstA,
       const float* __restrict__ consts,
       const __half* __restrict__ zh, const __half* __restrict__ hsb,
       __half* __restrict__ h16,
       const float* __restrict__ Wself, const float* __restrict__ Wfunc,
       const float* __restrict__ attn,
       __half* __restrict__ zh2, __half* __restrict__ hs2,
       float* __restrict__ s_src2, float* __restrict__ s_dst2) {
    __shared__ _Float16 wlds[2 * 64 * LDSW];   // 18 KB L2 weights
    __shared__ _Float16 hbuf[16 * 72];         // 2.3 KB h_new tile (A-frag layout)
    int tid = threadIdx.x;
    for (int idx = tid; idx < 2 * 64 * 64; idx += 512) {
        int mat = idx >> 12, rem = idx & 4095;
        int o = rem >> 6, k = rem & 63;
        float v = mat ? Wfunc[rem] : Wself[rem];
        wlds[(mat * 64 + o) * LDSW + k] = (_Float16)v;
    }

    int wave = tid >> 6, lane = tid & 63;
    int half = lane >> 5, hl = lane & 31;
    int eg = (lane >> 3) & 3, c8 = lane & 7;
    int n = blockIdx.x * 16 + wave * 2 + half;   // always < N_NODES (6250*16)
    int rs = rowStart[n];
    int deg = rowStart[n + 1] - rs;
    int degO = __shfl_xor(deg, 32);
    int degmax = deg > degO ? deg : degO;

    float c1 = consts[0];
    float c0 = consts[1];
    float sd = s_dstA[n];

    float acc[8];
#pragma unroll
    for (int k = 0; k < 8; ++k) acc[k] = 0.f;
    float ssl = 0.f;
    int lbase = lane & 32;

    for (int base = 0; base < degmax; base += 32) {
        float ex = 0.f;
        int s0 = 0;
        int idx = base + hl;
        if (idx < deg) {
            unsigned w = csr[rs + idx];
            s0 = (int)(w & 0x1FFFFu);
            float ew = (float)(w >> 17) * (1.f / 32768.f);
            float e = s_src[s0] + sd + ew * c1 + c0;
            e = (e > 0.f) ? e : NEG_SLOPE * e;
            ex = __expf(e);
        }
        ssl += ex;
        int cnt = degmax - base;
        if (cnt > 32) cnt = 32;
#pragma unroll 4
        for (int jb = 0; jb < cnt; jb += 4) {
            int srcl = lbase + jb + eg;
            int sj = __shfl(s0, srcl);
            float exj = __shfl(ex, srcl);
            unsigned boff = ((unsigned)sj << 7) | ((unsigned)c8 << 4);
            half8_t zv = *(const half8_t*)((const char*)zh + boff);
#pragma unroll
            for (int k = 0; k < 8; ++k) acc[k] += exj * (float)zv[k];
        }
    }
#pragma unroll
    for (int k = 0; k < 8; ++k) {
        acc[k] += __shfl_xor(acc[k], 8);
        acc[k] += __shfl_xor(acc[k], 16);
    }
    ssl += __shfl_xor(ssl, 16); ssl += __shfl_xor(ssl, 8);
    ssl += __shfl_xor(ssl, 4);  ssl += __shfl_xor(ssl, 2);
    ssl += __shfl_xor(ssl, 1);

    unsigned noff = ((unsigned)n << 7) | ((unsigned)c8 << 4);
    half8_t hv8 = *(const half8_t*)((const char*)h16 + noff);
    float hold[8];
#pragma unroll
    for (int k = 0; k < 8; ++k) hold[k] = (float)hv8[k];
    float hnew[8];
    if (deg == 0) {
#pragma unroll
        for (int k = 0; k < 8; ++k) hnew[k] = hold[k] + fmaxf(hold[k], 0.f);
    } else {
        float rinv = 1.f / ssl;
        half8_t hs8 = *(const half8_t*)((const char*)hsb + noff);
#pragma unroll
        for (int k = 0; k < 8; ++k)
            hnew[k] = hold[k] + fmaxf((float)hs8[k] + acc[k] * rinv, 0.f);
    }

    if (eg == 0) {
        half8_t o8;
#pragma unroll
        for (int k = 0; k < 8; ++k) o8[k] = (_Float16)hnew[k];
        *(half8_t*)((char*)h16 + noff) = o8;                    // residual for aggL2
        *(half8_t*)(hbuf + (wave * 2 + half) * 72 + c8 * 8) = o8;  // A-frag source
    }
    __syncthreads();

    if (wave == 0) {
        int quad = lane >> 4, lm = lane & 15;
        float asv[4], adv[4];
#pragma unroll
        for (int t = 0; t < 4; ++t) {
            asv[t] = attn[t * 16 + lm];
            adv[t] = attn[DH + t * 16 + lm];
        }
        half8_t afrag[2];
#pragma unroll
        for (int ks = 0; ks < 2; ++ks)
            afrag[ks] = *(const half8_t*)(hbuf + lm * 72 + ks * 32 + quad * 8);

        floatx4 accS[4], accF[4];
#pragma unroll
        for (int t = 0; t < 4; ++t) { accS[t] = (floatx4)0.f; accF[t] = (floatx4)0.f; }
        const _Float16* bS = wlds;
        const _Float16* bF = wlds + 64 * LDSW;
#pragma unroll
        for (int t = 0; t < 4; ++t) {
            int o = t * 16 + lm;
#pragma unroll
            for (int ks = 0; ks < 2; ++ks) {
                int hoff = o * LDSW + ks * 32 + quad * 8;
                half8_t b1 = *(const half8_t*)(bS + hoff);
                half8_t b2 = *(const half8_t*)(bF + hoff);
                accS[t] = __builtin_amdgcn_mfma_f32_16x16x32_f16(afrag[ks], b1, accS[t], 0, 0, 0);
                accF[t] = __builtin_amdgcn_mfma_f32_16x16x32_f16(afrag[ks], b2, accF[t], 0, 0, 0);
            }
        }

        int n0 = blockIdx.x * 16;
        float ps[4] = {0.f, 0.f, 0.f, 0.f}, pd[4] = {0.f, 0.f, 0.f, 0.f};
#pragma unroll
        for (int t = 0; t < 4; ++t) {
#pragma unroll
            for (int r = 0; r < 4; ++r) {
                int node = n0 + quad * 4 + r;
                float zv = accF[t][r];
                zh2[(size_t)node * DH + t * 16 + lm] = __float2half(zv);
                hs2[(size_t)node * DH + t * 16 + lm] = __float2half(accS[t][r]);
                ps[r] += zv * asv[t];
                pd[r] += zv * adv[t];
            }
        }
#pragma unroll
        for (int r = 0; r < 4; ++r) {
            float p1 = ps[r], p2 = pd[r];
            for (int off = 8; off; off >>= 1) {
                p1 += __shfl_xor(p1, off);
                p2 += __shfl_xor(p2, off);
            }
            if (lm == 0) {
                s_src2[n0 + quad * 4 + r] = p1;
                s_dst2[n0 + quad * 4 + r] = p2;
            }
        }
    }
}

// D7 (final layer): agg + fused projection (round-6 proven structure)
__global__ void k_agg(const int* __restrict__ rowStart,
                      const unsigned* __restrict__ csr,
                      const float* __restrict__ s_src, const float* __restrict__ s_dstA,
                      const float* __restrict__ consts, int layer,
                      const __half* __restrict__ zh, const __half* __restrict__ hsb,
                      __half* __restrict__ h16,
                      const float* __restrict__ lin_W, const float* __restrict__ lin_b,
                      float* __restrict__ y, int final_layer) {
    int wave = threadIdx.x >> 6, lane = threadIdx.x & 63;
    int half = lane >> 5, hl = lane & 31;
    int eg = (lane >> 3) & 3, c8 = lane & 7;
    int n = blockIdx.x * 8 + wave * 2 + half;
    if (n >= N_NODES) return;
    int rs = rowStart[n];
    int deg = rowStart[n + 1] - rs;
    int degO = __shfl_xor(deg, 32);
    int degmax = deg > degO ? deg : degO;

    float c1 = consts[layer * 2 + 0];
    float c0 = consts[layer * 2 + 1];
    float sd = s_dstA[n];

    float acc[8];
#pragma unroll
    for (int k = 0; k < 8; ++k) acc[k] = 0.f;
    float ssl = 0.f;
    int lbase = lane & 32;

    for (int base = 0; base < degmax; base += 32) {
        float ex = 0.f;
        int s0 = 0;
        int idx = base + hl;
        if (idx < deg) {
            unsigned w = csr[rs + idx];
            s0 = (int)(w & 0x1FFFFu);
            float ew = (float)(w >> 17) * (1.f / 32768.f);
            float e = s_src[s0] + sd + ew * c1 + c0;
            e = (e > 0.f) ? e : NEG_SLOPE * e;
            ex = __expf(e);
        }
        ssl += ex;
        int cnt = degmax - base;
        if (cnt > 32) cnt = 32;
#pragma unroll 4
        for (int jb = 0; jb < cnt; jb += 4) {
            int srcl = lbase + jb + eg;
            int sj = __shfl(s0, srcl);
            float exj = __shfl(ex, srcl);
            unsigned boff = ((unsigned)sj << 7) | ((unsigned)c8 << 4);
            half8_t zv = *(const half8_t*)((const char*)zh + boff);
#pragma unroll
            for (int k = 0; k < 8; ++k) acc[k] += exj * (float)zv[k];
        }
    }
#pragma unroll
    for (int k = 0; k < 8; ++k) {
        acc[k] += __shfl_xor(acc[k], 8);
        acc[k] += __shfl_xor(acc[k], 16);
    }
    ssl += __shfl_xor(ssl, 16); ssl += __shfl_xor(ssl, 8);
    ssl += __shfl_xor(ssl, 4);  ssl += __shfl_xor(ssl, 2);
    ssl += __shfl_xor(ssl, 1);

    unsigned noff = ((unsigned)n << 7) | ((unsigned)c8 << 4);
    half8_t hv8 = *(const half8_t*)((const char*)h16 + noff);
    float hold[8];
#pragma unroll
    for (int k = 0; k < 8; ++k) hold[k] = (float)hv8[k];
    float hnew[8];
    if (deg == 0) {
#pragma unroll
        for (int k = 0; k < 8; ++k) hnew[k] = hold[k] + fmaxf(hold[k], 0.f);
    } else {
        float rinv = 1.f / ssl;
        half8_t hs8 = *(const half8_t*)((const char*)hsb + noff);
#pragma unroll
        for (int k = 0; k < 8; ++k)
            hnew[k] = hold[k] + fmaxf((float)hs8[k] + acc[k] * rinv, 0.f);
    }

    if (!final_layer) {
        if (eg == 0) {
            half8_t o8;
#pragma unroll
            for (int k = 0; k < 8; ++k) o8[k] = (_Float16)hnew[k];
            *(half8_t*)((char*)h16 + noff) = o8;
        }
    } else {
#pragma unroll
        for (int t = 0; t < 3; ++t) {
            int o = eg * 3 + t;
            const float* wr = lin_W + o * DH + c8 * 8;
            float p = 0.f;
#pragma unroll
            for (int k = 0; k < 8; ++k) p += hnew[k] * wr[k];
            p += __shfl_xor(p, 1); p += __shfl_xor(p, 2); p += __shfl_xor(p, 4);
            if (c8 == 0) y[n * DOUT + o] = p + lin_b[o];
        }
    }
}

extern "C" void kernel_launch(void* const* d_in, const int* in_sizes, int n_in,
                              void* d_out, int out_size, void* d_ws, size_t ws_size,
                              hipStream_t stream) {
    const float* feats   = (const float*)d_in[0];
    const float* e_w     = (const float*)d_in[1];
    const int*   src     = (const int*)d_in[4];
    const int*   dst     = (const int*)d_in[5];
    const float* emb_h_W = (const float*)d_in[6];
    const float* emb_h_b = (const float*)d_in[7];
    const float* emb_e_W = (const float*)d_in[8];
    const float* emb_e_b = (const float*)d_in[9];
    const float* Wself[2] = {(const float*)d_in[10], (const float*)d_in[13]};
    const float* Wfunc[2] = {(const float*)d_in[11], (const float*)d_in[14]};
    const float* attn[2]  = {(const float*)d_in[12], (const float*)d_in[15]};
    const float* lin1_W  = (const float*)d_in[16];
    const float* lin1_b  = (const float*)d_in[17];
    float* y = (float*)d_out;

    char* ws = (char*)d_ws;
    size_t off = 0;
    auto alloc = [&](size_t bytes) {
        void* p = ws + off;
        off += (bytes + 255) & ~(size_t)255;
        return p;
    };
    __half*         h16      = (__half*)alloc((size_t)N_NODES * DH * 2);
    __half*         zh       = (__half*)alloc((size_t)N_NODES * DH * 2);
    __half*         hs16     = (__half*)alloc((size_t)N_NODES * DH * 2);
    __half*         zh2      = (__half*)alloc((size_t)N_NODES * DH * 2);
    __half*         hs2      = (__half*)alloc((size_t)N_NODES * DH * 2);
    unsigned*       csr2     = (unsigned*)alloc((size_t)N_EDGES * 4);
    float*          s_src    = (float*)alloc((size_t)N_NODES * 4);
    float*          s_dst    = (float*)alloc((size_t)N_NODES * 4);
    float*          s_src2   = (float*)alloc((size_t)N_NODES * 4);
    float*          s_dst2   = (float*)alloc((size_t)N_NODES * 4);
    int*            row_offN = (int*)alloc((size_t)(N_NODES + 1) * 4);
    int*            rowStart = (int*)alloc((size_t)(N_NODES + 1) * 4);
    unsigned char*  deg      = (unsigned char*)alloc((size_t)NTOT + 256);
    unsigned char*  chunkOff = (unsigned char*)alloc((size_t)NTOT + 256);
    unsigned char*  rank     = (unsigned char*)alloc((size_t)N_EDGES);
    int*            degN     = (int*)alloc((size_t)N_NODES * 4);
    int*            partN    = (int*)alloc(1024 * 4);
    float*          consts   = (float*)alloc(4 * 4);

    // D1: consts | hist(+rank)
    k_fuse1<<<1 + NB_HIST, 1024, 0, stream>>>(dst, deg, rank, emb_e_W, emb_e_b,
                                              attn[0], attn[1], consts);
    // D2: degN + chunkOff prefix
    k_prep2<<<NB_SUMDEG, 256, 0, stream>>>(deg, degN, chunkOff);
    // D3: scan1N
    k_prep3<<<NB_SCAN1N, 256, 0, stream>>>(degN, row_offN, partN);
    // D4: rowStart finalize (inline partN scan)
    k_prep4<<<NB_SUMDEG, 256, 0, stream>>>(row_offN, partN, rowStart);
    // D5: node GEMM L1(+embed) | scatter (1024-thr both, co-resident)
    k_fuse5<<<NB_NME + NB_SCAT4, 1024, 0, stream>>>(
        feats, emb_h_W, emb_h_b, h16, Wself[0], Wfunc[0], attn[0],
        zh, hs16, s_src, s_dst,
        src, dst, e_w, rank, rowStart, chunkOff, csr2);
    // D6: agg L1 + fused node GEMM L2
    k_aggG<<<NB_AGGG, 512, 0, stream>>>(rowStart, csr2, s_src, s_dst, consts,
                                        zh, hs16, h16, Wself[1], Wfunc[1], attn[1],
                                        zh2, hs2, s_src2, s_dst2);
    // D7: agg L2 + fused final projection
    k_agg<<<NB_AGG, 256, 0, stream>>>(rowStart, csr2, s_src2, s_dst2, consts, 1,
                                      zh2, hs2, h16, lin1_W, lin1_b, y, 1);
}

// Round 16
// 277.592 us; speedup vs baseline: 1.0852x; 1.0852x over previous
//
#include <hip/hip_runtime.h>
#include <hip/hip_fp16.h>

#define N_NODES 100000
#define N_EDGES 1600000
#define DIN 24
#define DH 64
#define DOUT 12
#define NEG_SLOPE 0.01f
#define NG 64                      // edge chunks
#define EPG (N_EDGES / NG)         // 25000 edges per chunk
#define NS 7                       // node slices for LDS hist
#define SLICE_N 16384              // nodes per slice (16 KB byte counters)
#define NTOT (NG * N_NODES)        // 6.4M (chunk,node) byte counters
#define SCAN_BLK 4096
#define LDSW 72

// role block counts
#define NB_HIST (NS * NG)                        // 448 (1024-thread blocks in D1)
#define NB_SUMDEG ((N_NODES + 255) / 256)               // 391
#define NB_SCAN1N ((N_NODES + SCAN_BLK - 1) / SCAN_BLK) // 25
#define NB_SCAT ((N_EDGES + 255) / 256)          // 6250 (1 edge/thread)
#define NB_NODE ((N_NODES + 63) / 64)            // 1563 tiles of 64 nodes
#define NB_NODE_T ((NB_NODE + 1) / 2)            // 782 blocks, 2 tiles each (L2)
#define NB_AGG ((N_NODES + 7) / 8)               // 12500

typedef _Float16 half8_t __attribute__((ext_vector_type(8)));
typedef float floatx4 __attribute__((ext_vector_type(4)));

// ---------------- role bodies ----------------
__device__ __forceinline__ void dev_consts(const float* emb_e_W, const float* emb_e_b,
                                           const float* attn1, const float* attn2,
                                           float* consts) {
    int lane = threadIdx.x;
    if (lane >= 64) return;
    float w = emb_e_W[lane], b = emb_e_b[lane];
    float a1 = attn1[2 * DH + lane], a2 = attn2[2 * DH + lane];
    float c11 = w * a1, c01 = b * a1, c12 = w * a2, c02 = b * a2;
    for (int off = 32; off; off >>= 1) {
        c11 += __shfl_down(c11, off);
        c01 += __shfl_down(c01, off);
        c12 += __shfl_down(c12, off);
        c02 += __shfl_down(c02, off);
    }
    if (lane == 0) {
        consts[0] = c11; consts[1] = c01; consts[2] = c12; consts[3] = c02;
    }
}

// slice-LDS histogram + rank capture, ZERO global atomics.
__device__ __forceinline__ void dev_hist(int bid, const int* dst,
                                         unsigned char* deg, unsigned char* rank) {
    __shared__ unsigned cnt[SLICE_N / 4];   // 16 KB byte-packed
    int s = bid % NS, c = bid / NS;
    for (int i = threadIdx.x; i < SLICE_N / 4; i += 1024) cnt[i] = 0;
    __syncthreads();
    int nbase = s * SLICE_N;
    int start = c * EPG, end = start + EPG;
    for (int i = start + threadIdx.x; i < end; i += 1024) {
        int local = dst[i] - nbase;
        if ((unsigned)local < SLICE_N) {
            unsigned sh = (unsigned)(local & 3) * 8u;
            unsigned old = atomicAdd(&cnt[local >> 2], 1u << sh);  // LDS atomic
            rank[i] = (unsigned char)((old >> sh) & 255u);
        }
    }
    __syncthreads();
    int nmax = N_NODES - nbase;
    if (nmax > SLICE_N) nmax = SLICE_N;
    unsigned* dw = (unsigned*)(deg + (size_t)c * N_NODES + nbase);
    for (int l = threadIdx.x; l < (nmax >> 2); l += 1024) dw[l] = cnt[l];
}

__device__ __forceinline__ void dev_scan1(int bid, const int* in, int* out,
                                          int* part, int n) {
    __shared__ int lds[256];
    int t = threadIdx.x;
    int base = bid * SCAN_BLK + t * 16;
    int v[16];
    int s = 0;
#pragma unroll
    for (int i = 0; i < 16; ++i) {
        int idx = base + i;
        v[i] = (idx < n) ? in[idx] : 0;
        s += v[i];
    }
    lds[t] = s;
    __syncthreads();
    for (int off = 1; off < 256; off <<= 1) {
        int y = (t >= off) ? lds[t - off] : 0;
        __syncthreads();
        lds[t] += y;
        __syncthreads();
    }
    int run = lds[t] - s;
#pragma unroll
    for (int i = 0; i < 16; ++i) {
        int idx = base + i;
        if (idx < n) out[idx] = run;
        run += v[i];
    }
    if (t == 255) part[bid] = lds[255];
}

// exclusive scan of part[0..nblk) + row_offN[N_NODES] tail fixup
__device__ __forceinline__ void dev_scan2(int* part, int nblk, int* row_offN) {
    __shared__ int lds2[256];
    int t = threadIdx.x;
    int v[4];
    int s = 0;
#pragma unroll
    for (int i = 0; i < 4; ++i) {
        int idx = t * 4 + i;
        v[i] = (idx < nblk) ? part[idx] : 0;
        s += v[i];
    }
    lds2[t] = s;
    __syncthreads();
    for (int off = 1; off < 256; off <<= 1) {
        int y = (t >= off) ? lds2[t - off] : 0;
        __syncthreads();
        lds2[t] += y;
        __syncthreads();
    }
    int run = lds2[t] - s;
#pragma unroll
    for (int i = 0; i < 4; ++i) {
        int idx = t * 4 + i;
        if (idx < nblk) part[idx] = run;
        run += v[i];
    }
    if (row_offN) {
        __syncthreads();
        if (t == 0) row_offN[N_NODES] = N_EDGES - part[N_NODES >> 12];
    }
}

// degN + per-node chunk prefix (byte)
__device__ __forceinline__ void dev_sumdeg(int bid, const unsigned char* degB,
                                           int* degN, unsigned char* chunkOff) {
    int n = bid * 256 + threadIdx.x;
    if (n >= N_NODES) return;
    int run = 0;
    for (int g = 0; g < NG; ++g) {
        size_t idx = (size_t)g * N_NODES + n;
        int v = (int)degB[idx];
        chunkOff[idx] = (unsigned char)run;
        run += v;
    }
    degN[n] = run;
}

// L1 node GEMM with FUSED embed; h and hs stored as f16.
__device__ __forceinline__ void dev_nodeME(int bid, int stride,
                                           const float* feats, const float* embW,
                                           const float* embB,
                                           const float* Wself, const float* Wfunc,
                                           const float* attn,
                                           __half* h16, __half* zh, __half* hs16,
                                           float* s_src, float* s_dst) {
    __shared__ _Float16 lds[2 * 64 * LDSW];   // 18 KB layer weights
    __shared__ _Float16 wembH[64 * 40];       // 5 KB embed weights (k pad 32, stride 40)
    __shared__ float biasS[64];
    __shared__ _Float16 hbufH[4][16 * 72];    // 9 KB per-wave h tiles (A-frag layout)
    int tid = threadIdx.x;
    for (int idx = tid; idx < 2 * 64 * 64; idx += 256) {
        int mat = idx >> 12, rem = idx & 4095;
        int o = rem >> 6, k = rem & 63;
        float v = mat ? Wfunc[rem] : Wself[rem];
        lds[(mat * 64 + o) * LDSW + k] = (_Float16)v;
    }
    for (int idx = tid; idx < 64 * 32; idx += 256) {
        int o = idx >> 5, k = idx & 31;
        wembH[o * 40 + k] = (_Float16)((k < DIN) ? embW[o * DIN + k] : 0.f);
    }
    if (tid < 64) biasS[tid] = embB[tid];
    __syncthreads();

    int wave = tid >> 6, lane = tid & 63;
    int quad = lane >> 4, lm = lane & 15;
    float asv[4], adv[4];
#pragma unroll
    for (int t = 0; t < 4; ++t) {
        asv[t] = attn[t * 16 + lm];
        adv[t] = attn[DH + t * 16 + lm];
    }
    const _Float16* bS = lds;
    const _Float16* bF = lds + 64 * LDSW;
    _Float16* hb = hbufH[wave];

    for (int tb = bid; tb < NB_NODE; tb += stride) {
        int n0 = (tb * 4 + wave) * 16;
        if (n0 >= N_NODES) continue;

        // ---- embed MFMA: A = feats rows (k = quad*8+j, valid k<24) ----
        half8_t afE;
#pragma unroll
        for (int j = 0; j < 8; ++j) afE[j] = (_Float16)0.f;
        if (quad < 3) {
            const float* f = feats + (size_t)(n0 + lm) * DIN + quad * 8;
            float4 q0 = *(const float4*)(f);
            float4 q1 = *(const float4*)(f + 4);
            afE[0] = (_Float16)q0.x; afE[1] = (_Float16)q0.y;
            afE[2] = (_Float16)q0.z; afE[3] = (_Float16)q0.w;
            afE[4] = (_Float16)q1.x; afE[5] = (_Float16)q1.y;
            afE[6] = (_Float16)q1.z; afE[7] = (_Float16)q1.w;
        }
        floatx4 accE[4];
#pragma unroll
        for (int t = 0; t < 4; ++t) accE[t] = (floatx4)0.f;
#pragma unroll
        for (int t = 0; t < 4; ++t) {
            int o = t * 16 + lm;
            half8_t bE = *(const half8_t*)(wembH + o * 40 + quad * 8);
            accE[t] = __builtin_amdgcn_mfma_f32_16x16x32_f16(afE, bE, accE[t], 0, 0, 0);
        }
        // bias + write h16 global (residual) + LDS hbuf (A-frag source)
#pragma unroll
        for (int t = 0; t < 4; ++t) {
            float bv = biasS[t * 16 + lm];
#pragma unroll
            for (int r = 0; r < 4; ++r) {
                float hv = accE[t][r] + bv;
                int node = n0 + quad * 4 + r;
                h16[(size_t)node * DH + t * 16 + lm] = __float2half(hv);
                hb[(quad * 4 + r) * 72 + t * 16 + lm] = (_Float16)hv;
            }
        }
        // same wave wrote all 16 rows of hb -> lockstep read, no barrier
        half8_t afrag[2];
#pragma unroll
        for (int ks = 0; ks < 2; ++ks)
            afrag[ks] = *(const half8_t*)(hb + lm * 72 + ks * 32 + quad * 8);

        floatx4 accS[4], accF[4];
#pragma unroll
        for (int t = 0; t < 4; ++t) { accS[t] = (floatx4)0.f; accF[t] = (floatx4)0.f; }
#pragma unroll
        for (int t = 0; t < 4; ++t) {
            int o = t * 16 + lm;
#pragma unroll
            for (int ks = 0; ks < 2; ++ks) {
                int hoff = o * LDSW + ks * 32 + quad * 8;
                half8_t b1 = *(const half8_t*)(bS + hoff);
                half8_t b2 = *(const half8_t*)(bF + hoff);
                accS[t] = __builtin_amdgcn_mfma_f32_16x16x32_f16(afrag[ks], b1, accS[t], 0, 0, 0);
                accF[t] = __builtin_amdgcn_mfma_f32_16x16x32_f16(afrag[ks], b2, accF[t], 0, 0, 0);
            }
        }

        float ps[4] = {0.f, 0.f, 0.f, 0.f}, pd[4] = {0.f, 0.f, 0.f, 0.f};
#pragma unroll
        for (int t = 0; t < 4; ++t) {
#pragma unroll
            for (int r = 0; r < 4; ++r) {
                int node = n0 + quad * 4 + r;
                float zv = accF[t][r];
                zh[(size_t)node * DH + t * 16 + lm] = __float2half(zv);
                hs16[(size_t)node * DH + t * 16 + lm] = __float2half(accS[t][r]);
                ps[r] += zv * asv[t];
                pd[r] += zv * adv[t];
            }
        }
#pragma unroll
        for (int r = 0; r < 4; ++r) {
            float p1 = ps[r], p2 = pd[r];
            for (int off = 8; off; off >>= 1) {
                p1 += __shfl_xor(p1, off);
                p2 += __shfl_xor(p2, off);
            }
            if (lm == 0) {
                s_src[n0 + quad * 4 + r] = p1;
                s_dst[n0 + quad * 4 + r] = p2;
            }
        }
    }
}

// L2 node GEMM: reads h16 directly into A-frags
__device__ __forceinline__ void dev_nodeM(int bid, int stride, const __half* h16,
                                          const float* Wself, const float* Wfunc,
                                          const float* attn,
                                          __half* zh, __half* hs16,
                                          float* s_src, float* s_dst) {
    __shared__ _Float16 lds[2 * 64 * LDSW];
    int tid = threadIdx.x;
    for (int idx = tid; idx < 2 * 64 * 64; idx += 256) {
        int mat = idx >> 12, rem = idx & 4095;
        int o = rem >> 6, k = rem & 63;
        float v = mat ? Wfunc[rem] : Wself[rem];
        lds[(mat * 64 + o) * LDSW + k] = (_Float16)v;
    }
    __syncthreads();

    int wave = tid >> 6, lane = tid & 63;
    int quad = lane >> 4, lm = lane & 15;
    float asv[4], adv[4];
#pragma unroll
    for (int t = 0; t < 4; ++t) {
        asv[t] = attn[t * 16 + lm];
        adv[t] = attn[DH + t * 16 + lm];
    }
    const _Float16* bS = lds;
    const _Float16* bF = lds + 64 * LDSW;

    for (int tb = bid; tb < NB_NODE; tb += stride) {
        int n0 = (tb * 4 + wave) * 16;
        if (n0 >= N_NODES) continue;

        const _Float16* hrow = (const _Float16*)h16 + (size_t)(n0 + lm) * DH;
        half8_t afrag[2];
#pragma unroll
        for (int ks = 0; ks < 2; ++ks)
            afrag[ks] = *(const half8_t*)(hrow + ks * 32 + quad * 8);

        floatx4 accS[4], accF[4];
#pragma unroll
        for (int t = 0; t < 4; ++t) { accS[t] = (floatx4)0.f; accF[t] = (floatx4)0.f; }

#pragma unroll
        for (int t = 0; t < 4; ++t) {
            int o = t * 16 + lm;
#pragma unroll
            for (int ks = 0; ks < 2; ++ks) {
                int hoff = o * LDSW + ks * 32 + quad * 8;
                half8_t b1 = *(const half8_t*)(bS + hoff);
                half8_t b2 = *(const half8_t*)(bF + hoff);
                accS[t] = __builtin_amdgcn_mfma_f32_16x16x32_f16(afrag[ks], b1, accS[t], 0, 0, 0);
                accF[t] = __builtin_amdgcn_mfma_f32_16x16x32_f16(afrag[ks], b2, accF[t], 0, 0, 0);
            }
        }

        float ps[4] = {0.f, 0.f, 0.f, 0.f}, pd[4] = {0.f, 0.f, 0.f, 0.f};
#pragma unroll
        for (int t = 0; t < 4; ++t) {
#pragma unroll
            for (int r = 0; r < 4; ++r) {
                int node = n0 + quad * 4 + r;
                float zv = accF[t][r];
                zh[(size_t)node * DH + t * 16 + lm] = __float2half(zv);
                hs16[(size_t)node * DH + t * 16 + lm] = __float2half(accS[t][r]);
                ps[r] += zv * asv[t];
                pd[r] += zv * adv[t];
            }
        }
#pragma unroll
        for (int r = 0; r < 4; ++r) {
            float p1 = ps[r], p2 = pd[r];
            for (int off = 8; off; off >>= 1) {
                p1 += __shfl_xor(p1, off);
                p2 += __shfl_xor(p2, off);
            }
            if (lm == 0) {
                s_src[n0 + quad * 4 + r] = p1;
                s_dst[n0 + quad * 4 + r] = p2;
            }
        }
    }
}

// ---------------- fused dispatches ----------------
// D1 (1024 thr): consts | hist only (448 blocks -> full chip round)
__global__ void __launch_bounds__(1024, 2)
k_fuse1(const int* __restrict__ dst, unsigned char* __restrict__ deg,
        unsigned char* __restrict__ rank,
        const float* __restrict__ emb_e_W, const float* __restrict__ emb_e_b,
        const float* __restrict__ attn1, const float* __restrict__ attn2,
        float* __restrict__ consts) {
    int bid = blockIdx.x;
    if (bid == 0) { dev_consts(emb_e_W, emb_e_b, attn1, attn2, consts); return; }
    dev_hist(bid - 1, dst, deg, rank);
}

// D2: node GEMM L1 + fused embed (long role first) | sumdeg+chunkOff
__global__ void __launch_bounds__(256, 4)
k_fuse2(const unsigned char* __restrict__ degB, int* __restrict__ degN,
        unsigned char* __restrict__ chunkOff,
        const float* __restrict__ feats, const float* __restrict__ embW,
        const float* __restrict__ embB,
        __half* __restrict__ h16, const float* __restrict__ Wself1,
        const float* __restrict__ Wfunc1, const float* __restrict__ attn1,
        __half* __restrict__ zh, __half* __restrict__ hs16,
        float* __restrict__ s_src, float* __restrict__ s_dst) {
    int bid = blockIdx.x;
    if (bid < NB_NODE_T) {
        dev_nodeME(bid, NB_NODE_T, feats, embW, embB, Wself1, Wfunc1, attn1,
                   h16, zh, hs16, s_src, s_dst);
        return;
    }
    dev_sumdeg(bid - NB_NODE_T, degB, degN, chunkOff);
}

// D3: scan1N
__global__ void k_prep3(const int* __restrict__ degN, int* __restrict__ row_offN,
                        int* __restrict__ partN) {
    dev_scan1(blockIdx.x, degN, row_offN, partN, N_NODES);
}

// D4: scan2N + tail
__global__ void k_prep4(int* __restrict__ partN, int* __restrict__ row_offN) {
    dev_scan2(partN, NB_SCAN1N, row_offN);
}

// D5: scatter, 1 edge/thread
__global__ void __launch_bounds__(256, 8)
k_scat(const int* __restrict__ src, const int* __restrict__ dst,
       const float* __restrict__ e_w, const unsigned char* __restrict__ rank,
       const int* __restrict__ row_offN, const int* __restrict__ partN,
       const unsigned char* __restrict__ chunkOff, unsigned* __restrict__ csr2) {
    int i = blockIdx.x * 256 + threadIdx.x;
    if (i >= N_EDGES) return;
    int g = i / EPG;
    int d = dst[i];
    unsigned qv = (unsigned)(e_w[i] * 32768.f);
    if (qv > 32767u) qv = 32767u;
    unsigned w = (unsigned)src[i] | (qv << 17);
    int pos = row_offN[d] + partN[d >> 12] + (int)chunkOff[(size_t)g * N_NODES + d]
            + (int)rank[i];
    csr2[pos] = w;
}

// D7: standalone layer-2 node GEMM (2 tiles/block, reads h16)
__global__ void __launch_bounds__(256, 4)
k_nodeL(const __half* __restrict__ h16, const float* __restrict__ Wself,
        const float* __restrict__ Wfunc, const float* __restrict__ attn,
        __half* __restrict__ zh, __half* __restrict__ hs16,
        float* __restrict__ s_src, float* __restrict__ s_dst) {
    dev_nodeM(blockIdx.x, NB_NODE_T, h16, Wself, Wfunc, attn, zh, hs16, s_src, s_dst);
}

// ---------------- fused edge softmax + aggregation + (optional) final projection --------
__global__ void k_agg(const int* __restrict__ row_off, const int* __restrict__ partN,
                      const unsigned* __restrict__ csr,
                      const float* __restrict__ s_src, const float* __restrict__ s_dstA,
                      const float* __restrict__ consts, int layer,
                      const __half* __restrict__ zh, const __half* __restrict__ hsb,
                      __half* __restrict__ h16,
                      const float* __restrict__ lin_W, const float* __restrict__ lin_b,
                      float* __restrict__ y, int final_layer) {
    int wave = threadIdx.x >> 6, lane = threadIdx.x & 63;
    int half = lane >> 5, hl = lane & 31;
    int eg = (lane >> 3) & 3, c8 = lane & 7;
    int n = blockIdx.x * 8 + wave * 2 + half;
    if (n >= N_NODES) return;
    int rs = row_off[n] + partN[n >> 12];
    int re = row_off[n + 1] + partN[(n + 1) >> 12];
    int deg = re - rs;
    int degO = __shfl_xor(deg, 32);
    int degmax = deg > degO ? deg : degO;

    float c1 = consts[layer * 2 + 0];
    float c0 = consts[layer * 2 + 1];
    float sd = s_dstA[n];

    float acc[8];
#pragma unroll
    for (int k = 0; k < 8; ++k) acc[k] = 0.f;
    float ssl = 0.f;
    int lbase = lane & 32;

    for (int base = 0; base < degmax; base += 32) {
        float ex = 0.f;
        int s0 = 0;
        int idx = base + hl;
        if (idx < deg) {
            unsigned w = csr[rs + idx];
            s0 = (int)(w & 0x1FFFFu);
            float ew = (float)(w >> 17) * (1.f / 32768.f);
            float e = s_src[s0] + sd + ew * c1 + c0;
            e = (e > 0.f) ? e : NEG_SLOPE * e;
            ex = __expf(e);
        }
        ssl += ex;
        int cnt = degmax - base;
        if (cnt > 32) cnt = 32;
#pragma unroll 4
        for (int jb = 0; jb < cnt; jb += 4) {
            int srcl = lbase + jb + eg;
            int sj = __shfl(s0, srcl);
            float exj = __shfl(ex, srcl);
            half8_t zv = *(const half8_t*)((const _Float16*)zh + ((size_t)sj << 6) + (c8 << 3));
#pragma unroll
            for (int k = 0; k < 8; ++k) acc[k] += exj * (float)zv[k];
        }
    }
#pragma unroll
    for (int k = 0; k < 8; ++k) {
        acc[k] += __shfl_xor(acc[k], 8);
        acc[k] += __shfl_xor(acc[k], 16);
    }
    ssl += __shfl_xor(ssl, 16); ssl += __shfl_xor(ssl, 8);
    ssl += __shfl_xor(ssl, 4);  ssl += __shfl_xor(ssl, 2);
    ssl += __shfl_xor(ssl, 1);

    half8_t hv8 = *(const half8_t*)((const _Float16*)h16 + (size_t)n * DH + (c8 << 3));
    float hold[8];
#pragma unroll
    for (int k = 0; k < 8; ++k) hold[k] = (float)hv8[k];
    float hnew[8];
    if (deg == 0) {
#pragma unroll
        for (int k = 0; k < 8; ++k) hnew[k] = hold[k] + fmaxf(hold[k], 0.f);
    } else {
        float rinv = 1.f / ssl;
        half8_t hs8 = *(const half8_t*)((const _Float16*)hsb + (size_t)n * DH + (c8 << 3));
#pragma unroll
        for (int k = 0; k < 8; ++k)
            hnew[k] = hold[k] + fmaxf((float)hs8[k] + acc[k] * rinv, 0.f);
    }

    if (!final_layer) {
        if (eg == 0) {
            half8_t o8;
#pragma unroll
            for (int k = 0; k < 8; ++k) o8[k] = (_Float16)hnew[k];
            *(half8_t*)((_Float16*)h16 + (size_t)n * DH + (c8 << 3)) = o8;
        }
    } else {
#pragma unroll
        for (int t = 0; t < 3; ++t) {
            int o = eg * 3 + t;
            const float* wr = lin_W + o * DH + c8 * 8;
            float p = 0.f;
#pragma unroll
            for (int k = 0; k < 8; ++k) p += hnew[k] * wr[k];
            p += __shfl_xor(p, 1); p += __shfl_xor(p, 2); p += __shfl_xor(p, 4);
            if (c8 == 0) y[n * DOUT + o] = p + lin_b[o];
        }
    }
}

extern "C" void kernel_launch(void* const* d_in, const int* in_sizes, int n_in,
                              void* d_out, int out_size, void* d_ws, size_t ws_size,
                              hipStream_t stream) {
    const float* feats   = (const float*)d_in[0];
    const float* e_w     = (const float*)d_in[1];
    const int*   src     = (const int*)d_in[4];
    const int*   dst     = (const int*)d_in[5];
    const float* emb_h_W = (const float*)d_in[6];
    const float* emb_h_b = (const float*)d_in[7];
    const float* emb_e_W = (const float*)d_in[8];
    const float* emb_e_b = (const float*)d_in[9];
    const float* Wself[2] = {(const float*)d_in[10], (const float*)d_in[13]};
    const float* Wfunc[2] = {(const float*)d_in[11], (const float*)d_in[14]};
    const float* attn[2]  = {(const float*)d_in[12], (const float*)d_in[15]};
    const float* lin1_W  = (const float*)d_in[16];
    const float* lin1_b  = (const float*)d_in[17];
    float* y = (float*)d_out;

    char* ws = (char*)d_ws;
    size_t off = 0;
    auto alloc = [&](size_t bytes) {
        void* p = ws + off;
        off += (bytes + 255) & ~(size_t)255;
        return p;
    };
    __half*         h16      = (__half*)alloc((size_t)N_NODES * DH * 2);
    __half*         zh       = (__half*)alloc((size_t)N_NODES * DH * 2);
    __half*         hs16     = (__half*)alloc((size_t)N_NODES * DH * 2);
    unsigned*       csr2     = (unsigned*)alloc((size_t)N_EDGES * 4);
    float*          s_src    = (float*)alloc((size_t)N_NODES * 4);
    float*          s_dst    = (float*)alloc((size_t)N_NODES * 4);
    int*            row_offN = (int*)alloc((size_t)(N_NODES + 1) * 4);
    unsigned char*  deg      = (unsigned char*)alloc((size_t)NTOT + 256);
    unsigned char*  chunkOff = (unsigned char*)alloc((size_t)NTOT + 256);
    unsigned char*  rank     = (unsigned char*)alloc((size_t)N_EDGES);
    int*            degN     = (int*)alloc((size_t)N_NODES * 4);
    int*            partN    = (int*)alloc(1024 * 4);
    float*          consts   = (float*)alloc(4 * 4);

    // D1: consts | slice-LDS hist(+rank), 448 blocks
    k_fuse1<<<1 + NB_HIST, 1024, 0, stream>>>(dst, deg, rank, emb_e_W, emb_e_b,
                                              attn[0], attn[1], consts);
    // D2: node GEMM L1 (+fused embed) | degN + chunkOff prefix
    k_fuse2<<<NB_NODE_T + NB_SUMDEG, 256, 0, stream>>>(
        deg, degN, chunkOff, feats, emb_h_W, emb_h_b,
        h16, Wself[0], Wfunc[0], attn[0], zh, hs16, s_src, s_dst);
    // D3: scan1N
    k_prep3<<<NB_SCAN1N, 256, 0, stream>>>(degN, row_offN, partN);
    // D4: scan2N + tail
    k_prep4<<<1, 256, 0, stream>>>(partN, row_offN);
    // D5: scatter (1 edge/thread, direct to csr2)
    k_scat<<<NB_SCAT, 256, 0, stream>>>(src, dst, e_w, rank, row_offN, partN,
                                        chunkOff, csr2);
    // D6: agg L1
    k_agg<<<NB_AGG, 256, 0, stream>>>(row_offN, partN, csr2, s_src, s_dst, consts, 0,
                                      zh, hs16, h16, lin1_W, lin1_b, y, 0);
    // D7: node GEMM L2
    k_nodeL<<<NB_NODE_T, 256, 0, stream>>>(h16, Wself[1], Wfunc[1], attn[1],
                                           zh, hs16, s_src, s_dst);
    // D8: agg L2 + fused final projection
    k_agg<<<NB_AGG, 256, 0, stream>>>(row_offN, partN, csr2, s_src, s_dst, consts, 1,
                                      zh, hs16, h16, lin1_W, lin1_b, y, 1);
}